// Round 13
// baseline (961.333 us; speedup 1.0000x reference)
//
#include <hip/hip_runtime.h>
#include <hip/hip_fp16.h>
#include <math.h>

#define NN 100000
#define EE 1600000
#define EP (EE + NN)   // edges incl. self-loops
#define NEG 0.2f
#define TN 128         // GEMM tile nodes
#define BW 256         // dst-bucket width
#define NB 391         // ceil(NN/BW)
#define CHUNK 4096     // partition chunk (8 edges/thread * 512)
#define SSTRIDE 5120   // arena slots per bucket (mean 4352, max ~4556 = +8 sd)
#define SCAP 5120      // LDS staging capacity in csr_scatter_k

typedef __attribute__((ext_vector_type(2))) float floatx2;

__device__ inline unsigned pk_fp8x4(float a, float b, float c, float d) {
    unsigned r = __builtin_amdgcn_cvt_pk_fp8_f32(a, b, 0u, false);
    r = __builtin_amdgcn_cvt_pk_fp8_f32(c, d, r, true);
    return r;
}

// Packed accumulate: 4x v_pk_fma_f32 instead of 8x v_fma_f32.
__device__ __forceinline__ void accum_fp8p(uint2 raw, float p, floatx2* acc) {
    floatx2 p2; p2[0] = p; p2[1] = p;
    acc[0] += p2 * __builtin_amdgcn_cvt_pk_f32_fp8(raw.x, false);
    acc[1] += p2 * __builtin_amdgcn_cvt_pk_f32_fp8(raw.x, true);
    acc[2] += p2 * __builtin_amdgcn_cvt_pk_f32_fp8(raw.y, false);
    acc[3] += p2 * __builtin_amdgcn_cvt_pk_f32_fp8(raw.y, true);
}

// Wave-level inclusive scan over 64 lanes.
__device__ __forceinline__ int wave_iscan(int v, int lane) {
#pragma unroll
    for (int o = 1; o < 64; o <<= 1) {
        int t = __shfl_up(v, o);
        if (lane >= o) v += t;
    }
    return v;
}

// ---------------- Bucketed CSR build (no pre-histogram) ----------------
// pack: val = (d_local<<17) | src  (d_local<256 -> 8 bits, src<2^17)
// arena strided per bucket; gcur[b] device cursor. Last partition block also
// performs the bucket scan (fused bscan): gcur[500] is the done counter.

__global__ __launch_bounds__(512) void partition_k(const int* __restrict__ ei, int* __restrict__ gcur,
                                                   unsigned int* __restrict__ arena,
                                                   int* __restrict__ bbase, int* __restrict__ rowptr) {
    __shared__ int lh[512], lcur[512], lbase[512];
    __shared__ int wsum[8];
    __shared__ unsigned int staged[CHUNK];
    __shared__ unsigned short stb[CHUNK];
    int tid = threadIdx.x;
    int lane = tid & 63, wid = tid >> 6;
    int c0 = blockIdx.x * CHUNK;
    int csize = min(CHUNK, EP - c0);
    lh[tid] = 0;
    __syncthreads();
    unsigned int myv[8];
    int myb[8];
#pragma unroll
    for (int i = 0; i < 8; i++) {
        int e = c0 + i * 512 + tid;
        if (e < c0 + csize) {
            int d = (e < EE) ? ei[EE + e] : (e - EE);
            int sv = (e < EE) ? ei[e] : d;
            int b = d >> 8;
            myv[i] = ((unsigned)(d - (b << 8)) << 17) | (unsigned)sv;
            myb[i] = b;
            atomicAdd(&lh[b], 1);
        } else myb[i] = -1;
    }
    __syncthreads();
    int v = lh[tid];
    int isc = wave_iscan(v, lane);
    if (lane == 63) wsum[wid] = isc;
    __syncthreads();
    if (tid == 0) {
        int run = 0;
#pragma unroll
        for (int w = 0; w < 8; w++) { int t = wsum[w]; wsum[w] = run; run += t; }
    }
    __syncthreads();
    int excl = isc - v + wsum[wid];
    lcur[tid] = excl;
    __syncthreads();
#pragma unroll
    for (int i = 0; i < 8; i++) {
        if (myb[i] >= 0) {
            int idx = atomicAdd(&lcur[myb[i]], 1);
            staged[idx] = myv[i];
            stb[idx] = (unsigned short)myb[i];
        }
    }
    __syncthreads();
    if (tid < NB && v > 0) {
        int base = atomicAdd(&gcur[tid], v);
        lbase[tid] = tid * SSTRIDE + base - excl;  // gidx = delta + staged idx
    }
    __syncthreads();
    for (int i = tid; i < csize; i += 512) {
        unsigned int val = staged[i];
        arena[lbase[stb[i]] + i] = val;
    }
    // ---- fused bucket scan: last block to finish scans gcur -> bbase ----
    __threadfence();
    __syncthreads();
    if (tid == 0) {
        unsigned prev = atomicAdd((unsigned int*)&gcur[500], 1u);
        lh[0] = (prev == (unsigned)(gridDim.x - 1)) ? 1 : 0;
    }
    __syncthreads();
    if (lh[0]) {
        __threadfence();
        int v2 = (tid < NB) ? gcur[tid] : 0;
        lcur[tid] = v2;
        __syncthreads();
        for (int o = 1; o < 512; o <<= 1) {
            int t = (tid >= o) ? lcur[tid - o] : 0;
            __syncthreads();
            lcur[tid] += t;
            __syncthreads();
        }
        int ex2 = lcur[tid] - v2;
        if (tid <= NB) bbase[tid] = ex2;   // bbase[NB] == EP
        if (tid == 0) rowptr[NN] = EP;
    }
}

// Also histograms per-dst degree into dbin (for degree-matched scheduling).
__global__ __launch_bounds__(512) void csr_scatter_k(const int* __restrict__ bbase, const int* __restrict__ gcur,
                                                     const unsigned int* __restrict__ arena,
                                                     int* __restrict__ rowptr, int* __restrict__ edge_src,
                                                     int* __restrict__ dbin) {
    __shared__ int cnt[256], sc[256];
    __shared__ int wsum[4];
    __shared__ unsigned int stg[SCAP];
    int tid = threadIdx.x;
    int b = blockIdx.x;
    int e0 = bbase[b];
    int sz = gcur[b];
    int abase = b * SSTRIDE;
    if (tid < 256) cnt[tid] = 0;
    __syncthreads();
    for (int i = tid; i < sz; i += 512) {
        unsigned int v = arena[abase + i];
        if (i < SCAP) stg[i] = v;
        atomicAdd(&cnt[v >> 17], 1);
    }
    __syncthreads();
    if (tid < 256) {
        int lane = tid & 63, wid = tid >> 6;
        int v = cnt[tid];
        int isc = wave_iscan(v, lane);
        if (lane == 63) wsum[wid] = isc;
        __syncthreads();
        if (tid == 0) {
            int run = 0;
#pragma unroll
            for (int w = 0; w < 4; w++) { int t = wsum[w]; wsum[w] = run; run += t; }
        }
        __syncthreads();
        int excl = isc - v + wsum[wid];
        int d = (b << 8) + tid;
        if (d < NN) {
            rowptr[d] = e0 + excl;
            atomicAdd(&dbin[v > 255 ? 255 : v], 1);
        }
        sc[tid] = excl;   // becomes per-dst cursor
    } else {
        __syncthreads();
        __syncthreads();
    }
    __syncthreads();
    for (int i = tid; i < sz; i += 512) {
        unsigned int val = (i < SCAP) ? stg[i] : arena[abase + i];
        int dl = val >> 17;
        int p = atomicAdd(&sc[dl], 1);
        edge_src[e0 + p] = (int)(val & 0x1FFFFu);
    }
}

// Degree-bin exclusive scan: dbin -> dcur (running cursors).
__global__ __launch_bounds__(256) void dscan_k(const int* __restrict__ dbin, int* __restrict__ dcur) {
    __shared__ int s[256];
    int tid = threadIdx.x;
    int v = dbin[tid];
    s[tid] = v;
    __syncthreads();
    for (int o = 1; o < 256; o <<= 1) {
        int t = (tid >= o) ? s[tid - o] : 0;
        __syncthreads();
        s[tid] += t;
        __syncthreads();
    }
    dcur[tid] = s[tid] - v;
}

// Scatter node ids into degree-sorted order.
__global__ __launch_bounds__(256) void dscatter_k(const int* __restrict__ rowptr, int* __restrict__ dcur,
                                                  int* __restrict__ porder) {
    int n = blockIdx.x * 256 + threadIdx.x;
    if (n >= NN) return;
    int deg = rowptr[n + 1] - rowptr[n];
    int bin = deg > 255 ? 255 : deg;
    int idx = atomicAdd(&dcur[bin], 1);
    porder[idx] = n;
}

// ---------------- Layer 0: rank-1 fused edge phase (degree-ordered) ----------------

__global__ __launch_bounds__(256) void gather0_k(const float* __restrict__ x, const float* __restrict__ W0,
                                                 const float* __restrict__ as_, const float* __restrict__ ad_,
                                                 const int* __restrict__ rowptr, const int* __restrict__ edge_src,
                                                 const int* __restrict__ porder,
                                                 const float* __restrict__ b, __half* __restrict__ hout) {
    __shared__ float W0l[64], asl[64], adl[64], bl[64];
    int tid = threadIdx.x;
    if (tid < 64) { W0l[tid] = W0[tid]; asl[tid] = as_[tid]; adl[tid] = ad_[tid]; bl[tid] = b[tid]; }
    __syncthreads();
    int pr = (blockIdx.x * 256 + tid) >> 6;
    int lane = tid & 63;
    if (pr >= NN) return;
    int wv = porder[pr];
    int q = lane >> 2, head = lane & 3;
    float cs = 0.f, cd = 0.f;
#pragma unroll
    for (int c = 0; c < 16; c++) {
        float w = W0l[head * 16 + c];
        cs += w * asl[head * 16 + c];
        cd += w * adl[head * 16 + c];
    }
    int beg = rowptr[wv], end = rowptr[wv + 1];
    float xd = x[wv];
    float num = 0.f, den = 0.f;
    for (int e0 = beg; e0 < end; e0 += 16) {
        int e = e0 + q;
        bool vld = e < end;
        int ee = vld ? e : (end - 1);
        int src = edge_src[ee];
        float xs = x[src];
        float ev = xs * cs + xd * cd;
        ev = ev > 0.f ? ev : NEG * ev;
        float p = vld ? __expf(ev) : 0.f;
        num += p * xs;
        den += p;
    }
    num += __shfl_xor(num, 4);  num += __shfl_xor(num, 8);
    num += __shfl_xor(num, 16); num += __shfl_xor(num, 32);
    den += __shfl_xor(den, 4);  den += __shfl_xor(den, 8);
    den += __shfl_xor(den, 16); den += __shfl_xor(den, 32);
    float nh = __shfl(num, lane >> 4);
    float dh = __shfl(den, lane >> 4);
    float val = nh / (dh + 1e-16f);
    float hv = val * W0l[lane] + bl[lane];
    hout[((size_t)wv << 6) + lane] = __float2half(hv);
}

// ---------------- 64x64 transform: tiled GEMM + fp8 + es/ed epilogue ----------------

__global__ __launch_bounds__(256) void transform64_k(const __half* __restrict__ hin, const float* __restrict__ W,
                                                     const float* __restrict__ as_, const float* __restrict__ ad_,
                                                     unsigned char* __restrict__ h8, float* __restrict__ es, float* __restrict__ ed) {
    __shared__ float At[64 * TN];   // At[k][n], 32 KB
    __shared__ float Wl[64 * 64];   // 16 KB
    int tid = threadIdx.x;
    for (int i = tid; i < 4096; i += 256) Wl[i] = W[i];
    int n0 = blockIdx.x * TN;
    {   // stage h tile transposed into At (fp16 -> fp32)
        int row = tid >> 1, hf = tid & 1;
        int n = n0 + row;
        const uint4* src = (const uint4*)(hin + ((size_t)n << 6) + (hf << 5));
#pragma unroll
        for (int i = 0; i < 4; i++) {
            uint4 raw = make_uint4(0, 0, 0, 0);
            if (n < NN) raw = src[i];
            __half2* hh = (__half2*)&raw;
            int c = (hf << 5) + (i << 3);
#pragma unroll
            for (int j = 0; j < 4; j++) {
                float2 f = __half22float2(hh[j]);
                At[(c + 2 * j) * TN + row]     = f.x;
                At[(c + 2 * j + 1) * TN + row] = f.y;
            }
        }
    }
    __syncthreads();
    int c = tid & 15, r = tid >> 4;
    float acc[8][4];
#pragma unroll
    for (int i = 0; i < 8; i++)
#pragma unroll
        for (int j = 0; j < 4; j++) acc[i][j] = 0.f;
#pragma unroll 4
    for (int k = 0; k < 64; k++) {
        float4 a0 = *(float4*)&At[k * TN + r * 8];
        float4 a1 = *(float4*)&At[k * TN + r * 8 + 4];
        float4 w  = *(float4*)&Wl[k * 64 + c * 4];
        float av[8] = {a0.x, a0.y, a0.z, a0.w, a1.x, a1.y, a1.z, a1.w};
#pragma unroll
        for (int i = 0; i < 8; i++) {
            acc[i][0] += av[i] * w.x; acc[i][1] += av[i] * w.y;
            acc[i][2] += av[i] * w.z; acc[i][3] += av[i] * w.w;
        }
    }
    int head = c >> 2, qq = c & 3;
    float as0v = as_[head * 16 + qq * 4], as1v = as_[head * 16 + qq * 4 + 1];
    float as2v = as_[head * 16 + qq * 4 + 2], as3v = as_[head * 16 + qq * 4 + 3];
    float ad0v = ad_[head * 16 + qq * 4], ad1v = ad_[head * 16 + qq * 4 + 1];
    float ad2v = ad_[head * 16 + qq * 4 + 2], ad3v = ad_[head * 16 + qq * 4 + 3];
#pragma unroll
    for (int i = 0; i < 8; i++) {
        int n = n0 + r * 8 + i;
        float pes = acc[i][0] * as0v + acc[i][1] * as1v + acc[i][2] * as2v + acc[i][3] * as3v;
        float ped = acc[i][0] * ad0v + acc[i][1] * ad1v + acc[i][2] * ad2v + acc[i][3] * ad3v;
        pes += __shfl_xor(pes, 1); pes += __shfl_xor(pes, 2);
        ped += __shfl_xor(ped, 1); ped += __shfl_xor(ped, 2);
        if (n < NN) {
            unsigned rq = pk_fp8x4(acc[i][0], acc[i][1], acc[i][2], acc[i][3]);
            *(unsigned*)(h8 + ((size_t)n << 6) + (c << 2)) = rq;
            if (qq == 0) { es[n * 4 + head] = pes; ed[n * 4 + head] = ped; }
        }
    }
}

// ---------------- Fused edge softmax + gather (degree-matched pairs) ----------------
// 2 nodes/wave from the degree-sorted permutation: matched degrees within a
// pair (iters = max -> ~mean) and uniform degrees across each block (no tail).
// lane = q*8+j; packed-f32 accumulation. Self-loops guarantee deg>=1.
// Max-subtraction dropped: |e| = O(1).

__global__ __launch_bounds__(256) void gather_k(const unsigned char* __restrict__ h8, const float* __restrict__ es,
                                                const float* __restrict__ ed, const int* __restrict__ rowptr,
                                                const int* __restrict__ edge_src, const int* __restrict__ porder,
                                                const float* __restrict__ b, __half* __restrict__ hout) {
    int pr = (blockIdx.x * 256 + threadIdx.x) >> 6;
    int lane = threadIdx.x & 63;
    if (pr * 2 >= NN) return;
    int nA = porder[pr * 2];
    int nB = (pr * 2 + 1 < NN) ? porder[pr * 2 + 1] : nA;
    int q = lane >> 3, j = lane & 7, head = j >> 1;
    const unsigned char* h8j = h8 + (j << 3);
    int begA = rowptr[nA], endA = rowptr[nA + 1];
    int begB = rowptr[nB], endB = rowptr[nB + 1];
    float edvA = ed[nA * 4 + head];
    float edvB = ed[nB * 4 + head];
    floatx2 accA[4], accB[4];
#pragma unroll
    for (int t = 0; t < 4; t++) { accA[t] = (floatx2)(0.f); accB[t] = (floatx2)(0.f); }
    float sA = 0.f, sB = 0.f;
    int iters = max((endA - begA + 7) >> 3, (endB - begB + 7) >> 3);
    for (int k = 0; k < iters; k++) {
        int eA = begA + (k << 3) + q;
        int eB = begB + (k << 3) + q;
        bool vA = eA < endA;
        bool vB = eB < endB;
        int srcA = edge_src[vA ? eA : begA];
        int srcB = edge_src[vB ? eB : begB];
        uint2 rawA = *(const uint2*)(h8j + ((unsigned)srcA << 6));
        float esvA = es[srcA * 4 + head];
        uint2 rawB = *(const uint2*)(h8j + ((unsigned)srcB << 6));
        float esvB = es[srcB * 4 + head];
        float evA = esvA + edvA; evA = evA > 0.f ? evA : NEG * evA;
        float evB = esvB + edvB; evB = evB > 0.f ? evB : NEG * evB;
        float pA = vA ? __expf(evA) : 0.f;
        float pB = vB ? __expf(evB) : 0.f;
        accum_fp8p(rawA, pA, accA);
        accum_fp8p(rawB, pB, accB);
        sA += pA;
        sB += pB;
    }
    float fA[8], fB[8];
#pragma unroll
    for (int t = 0; t < 4; t++) {
        fA[2 * t] = accA[t][0]; fA[2 * t + 1] = accA[t][1];
        fB[2 * t] = accB[t][0]; fB[2 * t + 1] = accB[t][1];
    }
#pragma unroll
    for (int t = 0; t < 8; t++) {
        fA[t] += __shfl_xor(fA[t], 8);
        fA[t] += __shfl_xor(fA[t], 16);
        fA[t] += __shfl_xor(fA[t], 32);
        fB[t] += __shfl_xor(fB[t], 8);
        fB[t] += __shfl_xor(fB[t], 16);
        fB[t] += __shfl_xor(fB[t], 32);
    }
    sA += __shfl_xor(sA, 8); sA += __shfl_xor(sA, 16); sA += __shfl_xor(sA, 32);
    sB += __shfl_xor(sB, 8); sB += __shfl_xor(sB, 16); sB += __shfl_xor(sB, 32);
    if (q == 0) {
        const float4* bp = (const float4*)(b + j * 8);
        float4 b0 = bp[0], b1 = bp[1];
        {
            float inv = 1.0f / (sA + 1e-16f);
            union { __half2 h2[4]; uint4 u; } pk;
            pk.h2[0] = __floats2half2_rn(fA[0] * inv + b0.x, fA[1] * inv + b0.y);
            pk.h2[1] = __floats2half2_rn(fA[2] * inv + b0.z, fA[3] * inv + b0.w);
            pk.h2[2] = __floats2half2_rn(fA[4] * inv + b1.x, fA[5] * inv + b1.y);
            pk.h2[3] = __floats2half2_rn(fA[6] * inv + b1.z, fA[7] * inv + b1.w);
            *(uint4*)(hout + ((size_t)nA << 6) + (j << 3)) = pk.u;
        }
        if (nB != nA) {
            float inv = 1.0f / (sB + 1e-16f);
            union { __half2 h2[4]; uint4 u; } pk;
            pk.h2[0] = __floats2half2_rn(fB[0] * inv + b0.x, fB[1] * inv + b0.y);
            pk.h2[1] = __floats2half2_rn(fB[2] * inv + b0.z, fB[3] * inv + b0.w);
            pk.h2[2] = __floats2half2_rn(fB[4] * inv + b1.x, fB[5] * inv + b1.y);
            pk.h2[3] = __floats2half2_rn(fB[6] * inv + b1.z, fB[7] * inv + b1.w);
            *(uint4*)(hout + ((size_t)nB << 6) + (j << 3)) = pk.u;
        }
    }
}

// ---------------- MLP + decoder + softmax (tiled, fused) ----------------

__global__ __launch_bounds__(256) void mlp_k(const __half* __restrict__ h, const float* __restrict__ lw1,
                                             const float* __restrict__ lb1, const float* __restrict__ lw2,
                                             const float* __restrict__ lb2, const float* __restrict__ dw,
                                             const float* __restrict__ db, float* __restrict__ out) {
    __shared__ float At[64 * TN];   // h tile transposed; reused as a1t after GEMM1
    __shared__ float W1l[4096];     // lw1; reused as a2t (needs 16*TN=2048)
    __shared__ float W2l[1024];
    __shared__ float dwl[64];
    __shared__ float dbl[4];
    int tid = threadIdx.x;
    for (int i = tid; i < 4096; i += 256) W1l[i] = lw1[i];
    for (int i = tid; i < 1024; i += 256) W2l[i] = lw2[i];
    if (tid < 64) dwl[tid] = dw[tid];
    if (tid < 4) dbl[tid] = db[tid];
    int n0 = blockIdx.x * TN;
    {   // stage
        int row = tid >> 1, hf = tid & 1;
        int n = n0 + row;
        const uint4* src = (const uint4*)(h + ((size_t)n << 6) + (hf << 5));
#pragma unroll
        for (int i = 0; i < 4; i++) {
            uint4 raw = make_uint4(0, 0, 0, 0);
            if (n < NN) raw = src[i];
            __half2* hh = (__half2*)&raw;
            int c = (hf << 5) + (i << 3);
#pragma unroll
            for (int j = 0; j < 4; j++) {
                float2 f = __half22float2(hh[j]);
                At[(c + 2 * j) * TN + row]     = f.x;
                At[(c + 2 * j + 1) * TN + row] = f.y;
            }
        }
    }
    __syncthreads();
    int c = tid & 15, r = tid >> 4;
    float acc[8][4];
#pragma unroll
    for (int i = 0; i < 8; i++)
#pragma unroll
        for (int j = 0; j < 4; j++) acc[i][j] = 0.f;
#pragma unroll 4
    for (int k = 0; k < 64; k++) {
        float4 a0 = *(float4*)&At[k * TN + r * 8];
        float4 a1 = *(float4*)&At[k * TN + r * 8 + 4];
        float4 w  = *(float4*)&W1l[k * 64 + c * 4];
        float av[8] = {a0.x, a0.y, a0.z, a0.w, a1.x, a1.y, a1.z, a1.w};
#pragma unroll
        for (int i = 0; i < 8; i++) {
            acc[i][0] += av[i] * w.x; acc[i][1] += av[i] * w.y;
            acc[i][2] += av[i] * w.z; acc[i][3] += av[i] * w.w;
        }
    }
    float b1v0 = lb1[c * 4], b1v1 = lb1[c * 4 + 1], b1v2 = lb1[c * 4 + 2], b1v3 = lb1[c * 4 + 3];
    __syncthreads();
#pragma unroll
    for (int i = 0; i < 8; i++) {
        int n = r * 8 + i;
        At[(c * 4 + 0) * TN + n] = fmaxf(acc[i][0] + b1v0, 0.f);
        At[(c * 4 + 1) * TN + n] = fmaxf(acc[i][1] + b1v1, 0.f);
        At[(c * 4 + 2) * TN + n] = fmaxf(acc[i][2] + b1v2, 0.f);
        At[(c * 4 + 3) * TN + n] = fmaxf(acc[i][3] + b1v3, 0.f);
    }
    __syncthreads();
    float acc2[8];
#pragma unroll
    for (int i = 0; i < 8; i++) acc2[i] = 0.f;
#pragma unroll 4
    for (int k = 0; k < 64; k++) {
        float4 a0 = *(float4*)&At[k * TN + r * 8];
        float4 a1 = *(float4*)&At[k * TN + r * 8 + 4];
        float wv = W2l[k * 16 + c];
        acc2[0] += a0.x * wv; acc2[1] += a0.y * wv; acc2[2] += a0.z * wv; acc2[3] += a0.w * wv;
        acc2[4] += a1.x * wv; acc2[5] += a1.y * wv; acc2[6] += a1.z * wv; acc2[7] += a1.w * wv;
    }
    float b2v = lb2[c];
#pragma unroll
    for (int i = 0; i < 8; i++) W1l[c * TN + r * 8 + i] = acc2[i] + b2v;  // a2t[col][node]
    __syncthreads();
    if (tid < TN) {
        int n = n0 + tid;
        if (n < NN) {
            float lg0 = dbl[0], lg1 = dbl[1], lg2 = dbl[2], lg3 = dbl[3];
#pragma unroll
            for (int k = 0; k < 16; k++) {
                float a = W1l[k * TN + tid];
                lg0 += a * dwl[k * 4];     lg1 += a * dwl[k * 4 + 1];
                lg2 += a * dwl[k * 4 + 2]; lg3 += a * dwl[k * 4 + 3];
            }
            float mx = fmaxf(fmaxf(lg0, lg1), fmaxf(lg2, lg3));
            float e0 = __expf(lg0 - mx), e1 = __expf(lg1 - mx), e2 = __expf(lg2 - mx), e3 = __expf(lg3 - mx);
            float inv = 1.0f / (e0 + e1 + e2 + e3);
            *(float4*)(out + (size_t)n * 4) = make_float4(e0 * inv, e1 * inv, e2 * inv, e3 * inv);
        }
    }
}

// ---------------- launch ----------------

extern "C" void kernel_launch(void* const* d_in, const int* in_sizes, int n_in,
                              void* d_out, int out_size, void* d_ws, size_t ws_size,
                              hipStream_t stream) {
    const float* x   = (const float*)d_in[0];
    const int*   ei  = (const int*)d_in[1];
    const float* W0  = (const float*)d_in[2];
    const float* as0 = (const float*)d_in[3];
    const float* ad0 = (const float*)d_in[4];
    const float* b0  = (const float*)d_in[5];
    const float* W1  = (const float*)d_in[6];
    const float* as1 = (const float*)d_in[7];
    const float* ad1 = (const float*)d_in[8];
    const float* b1  = (const float*)d_in[9];
    const float* W2  = (const float*)d_in[10];
    const float* as2 = (const float*)d_in[11];
    const float* ad2 = (const float*)d_in[12];
    const float* b2  = (const float*)d_in[13];
    const float* lw1 = (const float*)d_in[14];
    const float* lb1 = (const float*)d_in[15];
    const float* lw2 = (const float*)d_in[16];
    const float* lb2 = (const float*)d_in[17];
    const float* dw  = (const float*)d_in[18];
    const float* db  = (const float*)d_in[19];
    float* out = (float*)d_out;

    char* p = (char*)d_ws;
    size_t off = 0;
    auto alloc = [&](size_t n) -> void* {
        void* r = p + off;
        off = (off + n + 255) & ~(size_t)255;
        return r;
    };
    __half* hB     = (__half*)alloc((size_t)NN * 64 * 2);
    __half* hC     = (__half*)alloc((size_t)NN * 64 * 2);
    unsigned char* h8 = (unsigned char*)alloc((size_t)NN * 64);
    float*  es     = (float*)alloc((size_t)NN * 4 * 4);
    float*  ed     = (float*)alloc((size_t)NN * 4 * 4);
    int*    rowptr = (int*)alloc((size_t)(NN + 1) * 4);
    int*    edge_src = (int*)alloc((size_t)EP * 4);
    int*    porder = (int*)alloc((size_t)NN * 4);
    unsigned int* arena = (unsigned int*)alloc((size_t)NB * SSTRIDE * 4);
    int*    ints   = (int*)alloc(1024 * 4);   // [0..511]=gcur(+done@500), [512..767]=dbin, [768..1023]=dcur
    int*    bbase  = (int*)alloc(513 * 4);
    int* gcur = ints;
    int* dbin = ints + 512;
    int* dcur = ints + 768;

    hipMemsetAsync(ints, 0, 1024 * 4, stream);

    partition_k<<<(EP + CHUNK - 1) / CHUNK, 512, 0, stream>>>(ei, gcur, arena, bbase, rowptr);
    csr_scatter_k<<<NB, 512, 0, stream>>>(bbase, gcur, arena, rowptr, edge_src, dbin);
    dscan_k<<<1, 256, 0, stream>>>(dbin, dcur);
    dscatter_k<<<(NN + 255) / 256, 256, 0, stream>>>(rowptr, dcur, porder);

    int nb_tile = (NN + TN - 1) / TN;       // 782
    int nb_wave = (NN + 3) / 4;             // 25000
    int nb_pair = ((NN + 1) / 2 + 3) / 4;   // 12500 (2 nodes per wave)

    gather0_k<<<nb_wave, 256, 0, stream>>>(x, W0, as0, ad0, rowptr, edge_src, porder, b0, hB);

    transform64_k<<<nb_tile, 256, 0, stream>>>(hB, W1, as1, ad1, h8, es, ed);
    gather_k<<<nb_pair, 256, 0, stream>>>(h8, es, ed, rowptr, edge_src, porder, b1, hC);

    transform64_k<<<nb_tile, 256, 0, stream>>>(hC, W2, as2, ad2, h8, es, ed);
    gather_k<<<nb_pair, 256, 0, stream>>>(h8, es, ed, rowptr, edge_src, porder, b2, hB);

    mlp_k<<<nb_tile, 256, 0, stream>>>(hB, lw1, lb1, lw2, lb2, dw, db, out);
}

// Round 14
// 405.907 us; speedup vs baseline: 2.3684x; 2.3684x over previous
//
#include <hip/hip_runtime.h>
#include <hip/hip_fp16.h>
#include <math.h>

#define NN 100000
#define EE 1600000
#define EP (EE + NN)   // edges incl. self-loops
#define NEG 0.2f
#define TN 128         // GEMM tile nodes
#define BW 256         // dst-bucket width
#define NB 391         // ceil(NN/BW)
#define CHUNK 4096     // partition chunk (8 edges/thread * 512)
#define SSTRIDE 5120   // arena slots per bucket (mean 4352, max ~4556 = +8 sd)
#define SCAP 5120      // LDS staging capacity in csr_scatter_k

typedef __attribute__((ext_vector_type(2))) float floatx2;

__device__ inline unsigned pk_fp8x4(float a, float b, float c, float d) {
    unsigned r = __builtin_amdgcn_cvt_pk_fp8_f32(a, b, 0u, false);
    r = __builtin_amdgcn_cvt_pk_fp8_f32(c, d, r, true);
    return r;
}

// Packed accumulate: 4x v_pk_fma_f32 instead of 8x v_fma_f32.
__device__ __forceinline__ void accum_fp8p(uint2 raw, float p, floatx2* acc) {
    floatx2 p2; p2[0] = p; p2[1] = p;
    acc[0] += p2 * __builtin_amdgcn_cvt_pk_f32_fp8(raw.x, false);
    acc[1] += p2 * __builtin_amdgcn_cvt_pk_f32_fp8(raw.x, true);
    acc[2] += p2 * __builtin_amdgcn_cvt_pk_f32_fp8(raw.y, false);
    acc[3] += p2 * __builtin_amdgcn_cvt_pk_f32_fp8(raw.y, true);
}

// Wave-level inclusive scan over 64 lanes.
__device__ __forceinline__ int wave_iscan(int v, int lane) {
#pragma unroll
    for (int o = 1; o < 64; o <<= 1) {
        int t = __shfl_up(v, o);
        if (lane >= o) v += t;
    }
    return v;
}

// ---------------- Bucketed CSR build ----------------
// pack: val = (d_local<<17) | src  (d_local<256 -> 8 bits, src<2^17)
// arena strided per bucket; gcur[b] device cursor (one atomic per block per
// bucket — NEVER per element; r13 showed 100k contended global atomics on a
// tiny array cost ~300 us). Last partition block performs the bucket scan
// (fused bscan): gcur[500] is the done counter.

__global__ __launch_bounds__(512) void partition_k(const int* __restrict__ ei, int* __restrict__ gcur,
                                                   unsigned int* __restrict__ arena,
                                                   int* __restrict__ bbase, int* __restrict__ rowptr) {
    __shared__ int lh[512], lcur[512], lbase[512];
    __shared__ int wsum[8];
    __shared__ unsigned int staged[CHUNK];
    __shared__ unsigned short stb[CHUNK];
    int tid = threadIdx.x;
    int lane = tid & 63, wid = tid >> 6;
    int c0 = blockIdx.x * CHUNK;
    int csize = min(CHUNK, EP - c0);
    lh[tid] = 0;
    __syncthreads();
    unsigned int myv[8];
    int myb[8];
#pragma unroll
    for (int i = 0; i < 8; i++) {
        int e = c0 + i * 512 + tid;
        if (e < c0 + csize) {
            int d = (e < EE) ? ei[EE + e] : (e - EE);
            int sv = (e < EE) ? ei[e] : d;
            int b = d >> 8;
            myv[i] = ((unsigned)(d - (b << 8)) << 17) | (unsigned)sv;
            myb[i] = b;
            atomicAdd(&lh[b], 1);
        } else myb[i] = -1;
    }
    __syncthreads();
    int v = lh[tid];
    int isc = wave_iscan(v, lane);
    if (lane == 63) wsum[wid] = isc;
    __syncthreads();
    if (tid == 0) {
        int run = 0;
#pragma unroll
        for (int w = 0; w < 8; w++) { int t = wsum[w]; wsum[w] = run; run += t; }
    }
    __syncthreads();
    int excl = isc - v + wsum[wid];
    lcur[tid] = excl;
    __syncthreads();
#pragma unroll
    for (int i = 0; i < 8; i++) {
        if (myb[i] >= 0) {
            int idx = atomicAdd(&lcur[myb[i]], 1);
            staged[idx] = myv[i];
            stb[idx] = (unsigned short)myb[i];
        }
    }
    __syncthreads();
    if (tid < NB && v > 0) {
        int base = atomicAdd(&gcur[tid], v);
        lbase[tid] = tid * SSTRIDE + base - excl;  // gidx = delta + staged idx
    }
    __syncthreads();
    for (int i = tid; i < csize; i += 512) {
        unsigned int val = staged[i];
        arena[lbase[stb[i]] + i] = val;
    }
    // ---- fused bucket scan: last block to finish scans gcur -> bbase ----
    __threadfence();
    __syncthreads();
    if (tid == 0) {
        unsigned prev = atomicAdd((unsigned int*)&gcur[500], 1u);
        lh[0] = (prev == (unsigned)(gridDim.x - 1)) ? 1 : 0;
    }
    __syncthreads();
    if (lh[0]) {
        __threadfence();
        int v2 = (tid < NB) ? gcur[tid] : 0;
        lcur[tid] = v2;
        __syncthreads();
        for (int o = 1; o < 512; o <<= 1) {
            int t = (tid >= o) ? lcur[tid - o] : 0;
            __syncthreads();
            lcur[tid] += t;
            __syncthreads();
        }
        int ex2 = lcur[tid] - v2;
        if (tid <= NB) bbase[tid] = ex2;   // bbase[NB] == EP
        if (tid == 0) rowptr[NN] = EP;
    }
}

__global__ __launch_bounds__(512) void csr_scatter_k(const int* __restrict__ bbase, const int* __restrict__ gcur,
                                                     const unsigned int* __restrict__ arena,
                                                     int* __restrict__ rowptr, int* __restrict__ edge_src) {
    __shared__ int cnt[256], sc[256];
    __shared__ int wsum[4];
    __shared__ unsigned int stg[SCAP];
    int tid = threadIdx.x;
    int b = blockIdx.x;
    int e0 = bbase[b];
    int sz = gcur[b];
    int abase = b * SSTRIDE;
    if (tid < 256) cnt[tid] = 0;
    __syncthreads();
    for (int i = tid; i < sz; i += 512) {
        unsigned int v = arena[abase + i];
        if (i < SCAP) stg[i] = v;
        atomicAdd(&cnt[v >> 17], 1);
    }
    __syncthreads();
    if (tid < 256) {
        int lane = tid & 63, wid = tid >> 6;
        int v = cnt[tid];
        int isc = wave_iscan(v, lane);
        if (lane == 63) wsum[wid] = isc;
        __syncthreads();
        if (tid == 0) {
            int run = 0;
#pragma unroll
            for (int w = 0; w < 4; w++) { int t = wsum[w]; wsum[w] = run; run += t; }
        }
        __syncthreads();
        int excl = isc - v + wsum[wid];
        int d = (b << 8) + tid;
        if (d < NN) rowptr[d] = e0 + excl;
        sc[tid] = excl;   // becomes per-dst cursor
    } else {
        __syncthreads();
        __syncthreads();
    }
    __syncthreads();
    for (int i = tid; i < sz; i += 512) {
        unsigned int val = (i < SCAP) ? stg[i] : arena[abase + i];
        int dl = val >> 17;
        int p = atomicAdd(&sc[dl], 1);
        edge_src[e0 + p] = (int)(val & 0x1FFFFu);
    }
}

// ---------------- Layer 0: rank-1 fused edge phase ----------------

__global__ __launch_bounds__(256) void gather0_k(const float* __restrict__ x, const float* __restrict__ W0,
                                                 const float* __restrict__ as_, const float* __restrict__ ad_,
                                                 const int* __restrict__ rowptr, const int* __restrict__ edge_src,
                                                 const float* __restrict__ b, __half* __restrict__ hout) {
    __shared__ float W0l[64], asl[64], adl[64], bl[64];
    int tid = threadIdx.x;
    if (tid < 64) { W0l[tid] = W0[tid]; asl[tid] = as_[tid]; adl[tid] = ad_[tid]; bl[tid] = b[tid]; }
    __syncthreads();
    int wv = (blockIdx.x * 256 + tid) >> 6;
    int lane = tid & 63;
    if (wv >= NN) return;
    int q = lane >> 2, head = lane & 3;
    float cs = 0.f, cd = 0.f;
#pragma unroll
    for (int c = 0; c < 16; c++) {
        float w = W0l[head * 16 + c];
        cs += w * asl[head * 16 + c];
        cd += w * adl[head * 16 + c];
    }
    int beg = rowptr[wv], end = rowptr[wv + 1];
    float xd = x[wv];
    float num = 0.f, den = 0.f;
    for (int e0 = beg; e0 < end; e0 += 16) {
        int e = e0 + q;
        bool vld = e < end;
        int ee = vld ? e : (end - 1);
        int src = edge_src[ee];
        float xs = x[src];
        float ev = xs * cs + xd * cd;
        ev = ev > 0.f ? ev : NEG * ev;
        float p = vld ? __expf(ev) : 0.f;
        num += p * xs;
        den += p;
    }
    num += __shfl_xor(num, 4);  num += __shfl_xor(num, 8);
    num += __shfl_xor(num, 16); num += __shfl_xor(num, 32);
    den += __shfl_xor(den, 4);  den += __shfl_xor(den, 8);
    den += __shfl_xor(den, 16); den += __shfl_xor(den, 32);
    float nh = __shfl(num, lane >> 4);
    float dh = __shfl(den, lane >> 4);
    float val = nh / (dh + 1e-16f);
    float hv = val * W0l[lane] + bl[lane];
    hout[((size_t)wv << 6) + lane] = __float2half(hv);
}

// ---------------- 64x64 transform: tiled GEMM + fp8 + es/ed epilogue ----------------

__global__ __launch_bounds__(256) void transform64_k(const __half* __restrict__ hin, const float* __restrict__ W,
                                                     const float* __restrict__ as_, const float* __restrict__ ad_,
                                                     unsigned char* __restrict__ h8, float* __restrict__ es, float* __restrict__ ed) {
    __shared__ float At[64 * TN];   // At[k][n], 32 KB
    __shared__ float Wl[64 * 64];   // 16 KB
    int tid = threadIdx.x;
    for (int i = tid; i < 4096; i += 256) Wl[i] = W[i];
    int n0 = blockIdx.x * TN;
    {   // stage h tile transposed into At (fp16 -> fp32)
        int row = tid >> 1, hf = tid & 1;
        int n = n0 + row;
        const uint4* src = (const uint4*)(hin + ((size_t)n << 6) + (hf << 5));
#pragma unroll
        for (int i = 0; i < 4; i++) {
            uint4 raw = make_uint4(0, 0, 0, 0);
            if (n < NN) raw = src[i];
            __half2* hh = (__half2*)&raw;
            int c = (hf << 5) + (i << 3);
#pragma unroll
            for (int j = 0; j < 4; j++) {
                float2 f = __half22float2(hh[j]);
                At[(c + 2 * j) * TN + row]     = f.x;
                At[(c + 2 * j + 1) * TN + row] = f.y;
            }
        }
    }
    __syncthreads();
    int c = tid & 15, r = tid >> 4;
    float acc[8][4];
#pragma unroll
    for (int i = 0; i < 8; i++)
#pragma unroll
        for (int j = 0; j < 4; j++) acc[i][j] = 0.f;
#pragma unroll 4
    for (int k = 0; k < 64; k++) {
        float4 a0 = *(float4*)&At[k * TN + r * 8];
        float4 a1 = *(float4*)&At[k * TN + r * 8 + 4];
        float4 w  = *(float4*)&Wl[k * 64 + c * 4];
        float av[8] = {a0.x, a0.y, a0.z, a0.w, a1.x, a1.y, a1.z, a1.w};
#pragma unroll
        for (int i = 0; i < 8; i++) {
            acc[i][0] += av[i] * w.x; acc[i][1] += av[i] * w.y;
            acc[i][2] += av[i] * w.z; acc[i][3] += av[i] * w.w;
        }
    }
    int head = c >> 2, qq = c & 3;
    float as0v = as_[head * 16 + qq * 4], as1v = as_[head * 16 + qq * 4 + 1];
    float as2v = as_[head * 16 + qq * 4 + 2], as3v = as_[head * 16 + qq * 4 + 3];
    float ad0v = ad_[head * 16 + qq * 4], ad1v = ad_[head * 16 + qq * 4 + 1];
    float ad2v = ad_[head * 16 + qq * 4 + 2], ad3v = ad_[head * 16 + qq * 4 + 3];
#pragma unroll
    for (int i = 0; i < 8; i++) {
        int n = n0 + r * 8 + i;
        float pes = acc[i][0] * as0v + acc[i][1] * as1v + acc[i][2] * as2v + acc[i][3] * as3v;
        float ped = acc[i][0] * ad0v + acc[i][1] * ad1v + acc[i][2] * ad2v + acc[i][3] * ad3v;
        pes += __shfl_xor(pes, 1); pes += __shfl_xor(pes, 2);
        ped += __shfl_xor(ped, 1); ped += __shfl_xor(ped, 2);
        if (n < NN) {
            unsigned rq = pk_fp8x4(acc[i][0], acc[i][1], acc[i][2], acc[i][3]);
            *(unsigned*)(h8 + ((size_t)n << 6) + (c << 2)) = rq;
            if (qq == 0) { es[n * 4 + head] = pes; ed[n * 4 + head] = ped; }
        }
    }
}

// ---------------- Fused edge softmax + gather ----------------
// Best-measured config (r12): 2 nodes/wave, NO k-unroll, packed-f32
// accumulation, natural node order. lane = q*8+j; head = j>>1.
// Self-loops guarantee deg>=1. Max-subtraction dropped: |e| = O(1).

__global__ __launch_bounds__(256) void gather_k(const unsigned char* __restrict__ h8, const float* __restrict__ es,
                                                const float* __restrict__ ed, const int* __restrict__ rowptr,
                                                const int* __restrict__ edge_src, const float* __restrict__ b,
                                                __half* __restrict__ hout) {
    int pr = (blockIdx.x * 256 + threadIdx.x) >> 6;
    int lane = threadIdx.x & 63;
    int nA = pr * 2;
    if (nA >= NN) return;
    int nB = nA + 1;
    bool hasB = nB < NN;
    int q = lane >> 3, j = lane & 7, head = j >> 1;
    const unsigned char* h8j = h8 + (j << 3);
    int begA = rowptr[nA], endA = rowptr[nA + 1];
    int begB = hasB ? rowptr[nB] : begA, endB = hasB ? rowptr[nB + 1] : begA;
    float edvA = ed[nA * 4 + head];
    float edvB = hasB ? ed[nB * 4 + head] : 0.f;
    floatx2 accA[4], accB[4];
#pragma unroll
    for (int t = 0; t < 4; t++) { accA[t] = (floatx2)(0.f); accB[t] = (floatx2)(0.f); }
    float sA = 0.f, sB = 0.f;
    int iters = max((endA - begA + 7) >> 3, (endB - begB + 7) >> 3);
    for (int k = 0; k < iters; k++) {
        int eA = begA + (k << 3) + q;
        int eB = begB + (k << 3) + q;
        bool vA = eA < endA;
        bool vB = eB < endB;
        int srcA = edge_src[vA ? eA : begA];
        int srcB = edge_src[vB ? eB : begB];
        uint2 rawA = *(const uint2*)(h8j + ((unsigned)srcA << 6));
        float esvA = es[srcA * 4 + head];
        uint2 rawB = *(const uint2*)(h8j + ((unsigned)srcB << 6));
        float esvB = es[srcB * 4 + head];
        float evA = esvA + edvA; evA = evA > 0.f ? evA : NEG * evA;
        float evB = esvB + edvB; evB = evB > 0.f ? evB : NEG * evB;
        float pA = vA ? __expf(evA) : 0.f;
        float pB = vB ? __expf(evB) : 0.f;
        accum_fp8p(rawA, pA, accA);
        accum_fp8p(rawB, pB, accB);
        sA += pA;
        sB += pB;
    }
    float fA[8], fB[8];
#pragma unroll
    for (int t = 0; t < 4; t++) {
        fA[2 * t] = accA[t][0]; fA[2 * t + 1] = accA[t][1];
        fB[2 * t] = accB[t][0]; fB[2 * t + 1] = accB[t][1];
    }
#pragma unroll
    for (int t = 0; t < 8; t++) {
        fA[t] += __shfl_xor(fA[t], 8);
        fA[t] += __shfl_xor(fA[t], 16);
        fA[t] += __shfl_xor(fA[t], 32);
        fB[t] += __shfl_xor(fB[t], 8);
        fB[t] += __shfl_xor(fB[t], 16);
        fB[t] += __shfl_xor(fB[t], 32);
    }
    sA += __shfl_xor(sA, 8); sA += __shfl_xor(sA, 16); sA += __shfl_xor(sA, 32);
    sB += __shfl_xor(sB, 8); sB += __shfl_xor(sB, 16); sB += __shfl_xor(sB, 32);
    if (q == 0) {
        const float4* bp = (const float4*)(b + j * 8);
        float4 b0 = bp[0], b1 = bp[1];
        {
            float inv = 1.0f / (sA + 1e-16f);
            union { __half2 h2[4]; uint4 u; } pk;
            pk.h2[0] = __floats2half2_rn(fA[0] * inv + b0.x, fA[1] * inv + b0.y);
            pk.h2[1] = __floats2half2_rn(fA[2] * inv + b0.z, fA[3] * inv + b0.w);
            pk.h2[2] = __floats2half2_rn(fA[4] * inv + b1.x, fA[5] * inv + b1.y);
            pk.h2[3] = __floats2half2_rn(fA[6] * inv + b1.z, fA[7] * inv + b1.w);
            *(uint4*)(hout + ((size_t)nA << 6) + (j << 3)) = pk.u;
        }
        if (hasB) {
            float inv = 1.0f / (sB + 1e-16f);
            union { __half2 h2[4]; uint4 u; } pk;
            pk.h2[0] = __floats2half2_rn(fB[0] * inv + b0.x, fB[1] * inv + b0.y);
            pk.h2[1] = __floats2half2_rn(fB[2] * inv + b0.z, fB[3] * inv + b0.w);
            pk.h2[2] = __floats2half2_rn(fB[4] * inv + b1.x, fB[5] * inv + b1.y);
            pk.h2[3] = __floats2half2_rn(fB[6] * inv + b1.z, fB[7] * inv + b1.w);
            *(uint4*)(hout + ((size_t)nB << 6) + (j << 3)) = pk.u;
        }
    }
}

// ---------------- MLP + decoder + softmax (tiled, fused) ----------------

__global__ __launch_bounds__(256) void mlp_k(const __half* __restrict__ h, const float* __restrict__ lw1,
                                             const float* __restrict__ lb1, const float* __restrict__ lw2,
                                             const float* __restrict__ lb2, const float* __restrict__ dw,
                                             const float* __restrict__ db, float* __restrict__ out) {
    __shared__ float At[64 * TN];   // h tile transposed; reused as a1t after GEMM1
    __shared__ float W1l[4096];     // lw1; reused as a2t (needs 16*TN=2048)
    __shared__ float W2l[1024];
    __shared__ float dwl[64];
    __shared__ float dbl[4];
    int tid = threadIdx.x;
    for (int i = tid; i < 4096; i += 256) W1l[i] = lw1[i];
    for (int i = tid; i < 1024; i += 256) W2l[i] = lw2[i];
    if (tid < 64) dwl[tid] = dw[tid];
    if (tid < 4) dbl[tid] = db[tid];
    int n0 = blockIdx.x * TN;
    {   // stage
        int row = tid >> 1, hf = tid & 1;
        int n = n0 + row;
        const uint4* src = (const uint4*)(h + ((size_t)n << 6) + (hf << 5));
#pragma unroll
        for (int i = 0; i < 4; i++) {
            uint4 raw = make_uint4(0, 0, 0, 0);
            if (n < NN) raw = src[i];
            __half2* hh = (__half2*)&raw;
            int c = (hf << 5) + (i << 3);
#pragma unroll
            for (int j = 0; j < 4; j++) {
                float2 f = __half22float2(hh[j]);
                At[(c + 2 * j) * TN + row]     = f.x;
                At[(c + 2 * j + 1) * TN + row] = f.y;
            }
        }
    }
    __syncthreads();
    int c = tid & 15, r = tid >> 4;
    float acc[8][4];
#pragma unroll
    for (int i = 0; i < 8; i++)
#pragma unroll
        for (int j = 0; j < 4; j++) acc[i][j] = 0.f;
#pragma unroll 4
    for (int k = 0; k < 64; k++) {
        float4 a0 = *(float4*)&At[k * TN + r * 8];
        float4 a1 = *(float4*)&At[k * TN + r * 8 + 4];
        float4 w  = *(float4*)&W1l[k * 64 + c * 4];
        float av[8] = {a0.x, a0.y, a0.z, a0.w, a1.x, a1.y, a1.z, a1.w};
#pragma unroll
        for (int i = 0; i < 8; i++) {
            acc[i][0] += av[i] * w.x; acc[i][1] += av[i] * w.y;
            acc[i][2] += av[i] * w.z; acc[i][3] += av[i] * w.w;
        }
    }
    float b1v0 = lb1[c * 4], b1v1 = lb1[c * 4 + 1], b1v2 = lb1[c * 4 + 2], b1v3 = lb1[c * 4 + 3];
    __syncthreads();
#pragma unroll
    for (int i = 0; i < 8; i++) {
        int n = r * 8 + i;
        At[(c * 4 + 0) * TN + n] = fmaxf(acc[i][0] + b1v0, 0.f);
        At[(c * 4 + 1) * TN + n] = fmaxf(acc[i][1] + b1v1, 0.f);
        At[(c * 4 + 2) * TN + n] = fmaxf(acc[i][2] + b1v2, 0.f);
        At[(c * 4 + 3) * TN + n] = fmaxf(acc[i][3] + b1v3, 0.f);
    }
    __syncthreads();
    float acc2[8];
#pragma unroll
    for (int i = 0; i < 8; i++) acc2[i] = 0.f;
#pragma unroll 4
    for (int k = 0; k < 64; k++) {
        float4 a0 = *(float4*)&At[k * TN + r * 8];
        float4 a1 = *(float4*)&At[k * TN + r * 8 + 4];
        float wv = W2l[k * 16 + c];
        acc2[0] += a0.x * wv; acc2[1] += a0.y * wv; acc2[2] += a0.z * wv; acc2[3] += a0.w * wv;
        acc2[4] += a1.x * wv; acc2[5] += a1.y * wv; acc2[6] += a1.z * wv; acc2[7] += a1.w * wv;
    }
    float b2v = lb2[c];
#pragma unroll
    for (int i = 0; i < 8; i++) W1l[c * TN + r * 8 + i] = acc2[i] + b2v;  // a2t[col][node]
    __syncthreads();
    if (tid < TN) {
        int n = n0 + tid;
        if (n < NN) {
            float lg0 = dbl[0], lg1 = dbl[1], lg2 = dbl[2], lg3 = dbl[3];
#pragma unroll
            for (int k = 0; k < 16; k++) {
                float a = W1l[k * TN + tid];
                lg0 += a * dwl[k * 4];     lg1 += a * dwl[k * 4 + 1];
                lg2 += a * dwl[k * 4 + 2]; lg3 += a * dwl[k * 4 + 3];
            }
            float mx = fmaxf(fmaxf(lg0, lg1), fmaxf(lg2, lg3));
            float e0 = __expf(lg0 - mx), e1 = __expf(lg1 - mx), e2 = __expf(lg2 - mx), e3 = __expf(lg3 - mx);
            float inv = 1.0f / (e0 + e1 + e2 + e3);
            *(float4*)(out + (size_t)n * 4) = make_float4(e0 * inv, e1 * inv, e2 * inv, e3 * inv);
        }
    }
}

// ---------------- launch ----------------

extern "C" void kernel_launch(void* const* d_in, const int* in_sizes, int n_in,
                              void* d_out, int out_size, void* d_ws, size_t ws_size,
                              hipStream_t stream) {
    const float* x   = (const float*)d_in[0];
    const int*   ei  = (const int*)d_in[1];
    const float* W0  = (const float*)d_in[2];
    const float* as0 = (const float*)d_in[3];
    const float* ad0 = (const float*)d_in[4];
    const float* b0  = (const float*)d_in[5];
    const float* W1  = (const float*)d_in[6];
    const float* as1 = (const float*)d_in[7];
    const float* ad1 = (const float*)d_in[8];
    const float* b1  = (const float*)d_in[9];
    const float* W2  = (const float*)d_in[10];
    const float* as2 = (const float*)d_in[11];
    const float* ad2 = (const float*)d_in[12];
    const float* b2  = (const float*)d_in[13];
    const float* lw1 = (const float*)d_in[14];
    const float* lb1 = (const float*)d_in[15];
    const float* lw2 = (const float*)d_in[16];
    const float* lb2 = (const float*)d_in[17];
    const float* dw  = (const float*)d_in[18];
    const float* db  = (const float*)d_in[19];
    float* out = (float*)d_out;

    char* p = (char*)d_ws;
    size_t off = 0;
    auto alloc = [&](size_t n) -> void* {
        void* r = p + off;
        off = (off + n + 255) & ~(size_t)255;
        return r;
    };
    __half* hB     = (__half*)alloc((size_t)NN * 64 * 2);
    __half* hC     = (__half*)alloc((size_t)NN * 64 * 2);
    unsigned char* h8 = (unsigned char*)alloc((size_t)NN * 64);
    float*  es     = (float*)alloc((size_t)NN * 4 * 4);
    float*  ed     = (float*)alloc((size_t)NN * 4 * 4);
    int*    rowptr = (int*)alloc((size_t)(NN + 1) * 4);
    int*    edge_src = (int*)alloc((size_t)EP * 4);
    unsigned int* arena = (unsigned int*)alloc((size_t)NB * SSTRIDE * 4);
    int*    gcur   = (int*)alloc(512 * 4);
    int*    bbase  = (int*)alloc(513 * 4);

    hipMemsetAsync(gcur, 0, 512 * 4, stream);

    partition_k<<<(EP + CHUNK - 1) / CHUNK, 512, 0, stream>>>(ei, gcur, arena, bbase, rowptr);
    csr_scatter_k<<<NB, 512, 0, stream>>>(bbase, gcur, arena, rowptr, edge_src);

    int nb_tile = (NN + TN - 1) / TN;       // 782
    int nb_wave = (NN + 3) / 4;             // 25000
    int nb_pair = ((NN + 1) / 2 + 3) / 4;   // 12500 (2 nodes per wave)

    gather0_k<<<nb_wave, 256, 0, stream>>>(x, W0, as0, ad0, rowptr, edge_src, b0, hB);

    transform64_k<<<nb_tile, 256, 0, stream>>>(hB, W1, as1, ad1, h8, es, ed);
    gather_k<<<nb_pair, 256, 0, stream>>>(h8, es, ed, rowptr, edge_src, b1, hC);

    transform64_k<<<nb_tile, 256, 0, stream>>>(hC, W2, as2, ad2, h8, es, ed);
    gather_k<<<nb_pair, 256, 0, stream>>>(h8, es, ed, rowptr, edge_src, b2, hB);

    mlp_k<<<nb_tile, 256, 0, stream>>>(hB, lw1, lb1, lw2, lb2, dw, db, out);
}

// Round 15
// 307.733 us; speedup vs baseline: 3.1239x; 1.3190x over previous
//
#include <hip/hip_runtime.h>
#include <hip/hip_fp16.h>
#include <math.h>

#define NN 100000
#define EE 1600000
#define EP (EE + NN)   // edges incl. self-loops
#define NEG 0.2f
#define TN 128         // GEMM tile nodes
#define BW 256         // dst-bucket width
#define NB 391         // ceil(NN/BW)
#define CHUNK 4096     // partition chunk (8 edges/thread * 512)
#define SSTRIDE 5120   // arena slots per bucket (mean 4352, max ~4556 = +8 sd)
#define SCAP 5120      // LDS staging capacity in csr_scatter_k

typedef __attribute__((ext_vector_type(2))) float floatx2;

__device__ inline unsigned pk_fp8x4(float a, float b, float c, float d) {
    unsigned r = __builtin_amdgcn_cvt_pk_fp8_f32(a, b, 0u, false);
    r = __builtin_amdgcn_cvt_pk_fp8_f32(c, d, r, true);
    return r;
}

// Packed accumulate: 4x v_pk_fma_f32 instead of 8x v_fma_f32.
__device__ __forceinline__ void accum_fp8p(uint2 raw, float p, floatx2* acc) {
    floatx2 p2; p2[0] = p; p2[1] = p;
    acc[0] += p2 * __builtin_amdgcn_cvt_pk_f32_fp8(raw.x, false);
    acc[1] += p2 * __builtin_amdgcn_cvt_pk_f32_fp8(raw.x, true);
    acc[2] += p2 * __builtin_amdgcn_cvt_pk_f32_fp8(raw.y, false);
    acc[3] += p2 * __builtin_amdgcn_cvt_pk_f32_fp8(raw.y, true);
}

// Wave-level inclusive scan over 64 lanes.
__device__ __forceinline__ int wave_iscan(int v, int lane) {
#pragma unroll
    for (int o = 1; o < 64; o <<= 1) {
        int t = __shfl_up(v, o);
        if (lane >= o) v += t;
    }
    return v;
}

// ---------------- Bucketed CSR build (no pre-histogram) ----------------
// pack: val = (d_local<<17) | src  (d_local<256 -> 8 bits, src<2^17)
// arena strided per bucket; gcur[b] device cursor — one atomic per block per
// bucket, NEVER per element (r13: 100k contended global atomics ~ 300 us).
// NO device-scope threadfence chains (r14: fence after scattered writes ~
// 100 us/dispatch); the bscan_k launch boundary is the cheap fence.

__global__ __launch_bounds__(512) void partition_k(const int* __restrict__ ei, int* __restrict__ gcur,
                                                   unsigned int* __restrict__ arena) {
    __shared__ int lh[512], lcur[512], lbase[512];
    __shared__ int wsum[8];
    __shared__ unsigned int staged[CHUNK];
    __shared__ unsigned short stb[CHUNK];
    int tid = threadIdx.x;
    int lane = tid & 63, wid = tid >> 6;
    int c0 = blockIdx.x * CHUNK;
    int csize = min(CHUNK, EP - c0);
    lh[tid] = 0;
    __syncthreads();
    unsigned int myv[8];
    int myb[8];
#pragma unroll
    for (int i = 0; i < 8; i++) {
        int e = c0 + i * 512 + tid;
        if (e < c0 + csize) {
            int d = (e < EE) ? ei[EE + e] : (e - EE);
            int sv = (e < EE) ? ei[e] : d;
            int b = d >> 8;
            myv[i] = ((unsigned)(d - (b << 8)) << 17) | (unsigned)sv;
            myb[i] = b;
            atomicAdd(&lh[b], 1);
        } else myb[i] = -1;
    }
    __syncthreads();
    int v = lh[tid];
    int isc = wave_iscan(v, lane);
    if (lane == 63) wsum[wid] = isc;
    __syncthreads();
    if (tid == 0) {
        int run = 0;
#pragma unroll
        for (int w = 0; w < 8; w++) { int t = wsum[w]; wsum[w] = run; run += t; }
    }
    __syncthreads();
    int excl = isc - v + wsum[wid];
    lcur[tid] = excl;
    __syncthreads();
#pragma unroll
    for (int i = 0; i < 8; i++) {
        if (myb[i] >= 0) {
            int idx = atomicAdd(&lcur[myb[i]], 1);
            staged[idx] = myv[i];
            stb[idx] = (unsigned short)myb[i];
        }
    }
    __syncthreads();
    if (tid < NB && v > 0) {
        int base = atomicAdd(&gcur[tid], v);
        lbase[tid] = tid * SSTRIDE + base - excl;  // gidx = delta + staged idx
    }
    __syncthreads();
    for (int i = tid; i < csize; i += 512) {
        unsigned int val = staged[i];
        arena[lbase[stb[i]] + i] = val;
    }
}

__global__ __launch_bounds__(512) void bscan_k(const int* __restrict__ gcur, int* __restrict__ bbase,
                                               int* __restrict__ rowptr) {
    __shared__ int s[512];
    int tid = threadIdx.x;
    int v = (tid < NB) ? gcur[tid] : 0;
    s[tid] = v;
    __syncthreads();
    for (int o = 1; o < 512; o <<= 1) {
        int t = (tid >= o) ? s[tid - o] : 0;
        __syncthreads();
        s[tid] += t;
        __syncthreads();
    }
    int excl = s[tid] - v;
    if (tid <= NB) bbase[tid] = excl;   // bbase[NB] == EP
    if (tid == 0) rowptr[NN] = EP;
}

__global__ __launch_bounds__(512) void csr_scatter_k(const int* __restrict__ bbase, const int* __restrict__ gcur,
                                                     const unsigned int* __restrict__ arena,
                                                     int* __restrict__ rowptr, int* __restrict__ edge_src) {
    __shared__ int cnt[256], sc[256];
    __shared__ int wsum[4];
    __shared__ unsigned int stg[SCAP];
    int tid = threadIdx.x;
    int b = blockIdx.x;
    int e0 = bbase[b];
    int sz = gcur[b];
    int abase = b * SSTRIDE;
    if (tid < 256) cnt[tid] = 0;
    __syncthreads();
    for (int i = tid; i < sz; i += 512) {
        unsigned int v = arena[abase + i];
        if (i < SCAP) stg[i] = v;
        atomicAdd(&cnt[v >> 17], 1);
    }
    __syncthreads();
    if (tid < 256) {
        int lane = tid & 63, wid = tid >> 6;
        int v = cnt[tid];
        int isc = wave_iscan(v, lane);
        if (lane == 63) wsum[wid] = isc;
        __syncthreads();
        if (tid == 0) {
            int run = 0;
#pragma unroll
            for (int w = 0; w < 4; w++) { int t = wsum[w]; wsum[w] = run; run += t; }
        }
        __syncthreads();
        int excl = isc - v + wsum[wid];
        int d = (b << 8) + tid;
        if (d < NN) rowptr[d] = e0 + excl;
        sc[tid] = excl;   // becomes per-dst cursor
    } else {
        __syncthreads();
        __syncthreads();
    }
    __syncthreads();
    for (int i = tid; i < sz; i += 512) {
        unsigned int val = (i < SCAP) ? stg[i] : arena[abase + i];
        int dl = val >> 17;
        int p = atomicAdd(&sc[dl], 1);
        edge_src[e0 + p] = (int)(val & 0x1FFFFu);
    }
}

// ---------------- Layer 0: rank-1 fused edge phase ----------------

__global__ __launch_bounds__(256) void gather0_k(const float* __restrict__ x, const float* __restrict__ W0,
                                                 const float* __restrict__ as_, const float* __restrict__ ad_,
                                                 const int* __restrict__ rowptr, const int* __restrict__ edge_src,
                                                 const float* __restrict__ b, __half* __restrict__ hout) {
    __shared__ float W0l[64], asl[64], adl[64], bl[64];
    int tid = threadIdx.x;
    if (tid < 64) { W0l[tid] = W0[tid]; asl[tid] = as_[tid]; adl[tid] = ad_[tid]; bl[tid] = b[tid]; }
    __syncthreads();
    int wv = (blockIdx.x * 256 + tid) >> 6;
    int lane = tid & 63;
    if (wv >= NN) return;
    int q = lane >> 2, head = lane & 3;
    float cs = 0.f, cd = 0.f;
#pragma unroll
    for (int c = 0; c < 16; c++) {
        float w = W0l[head * 16 + c];
        cs += w * asl[head * 16 + c];
        cd += w * adl[head * 16 + c];
    }
    int beg = rowptr[wv], end = rowptr[wv + 1];
    float xd = x[wv];
    float num = 0.f, den = 0.f;
    for (int e0 = beg; e0 < end; e0 += 16) {
        int e = e0 + q;
        bool vld = e < end;
        int ee = vld ? e : (end - 1);
        int src = edge_src[ee];
        float xs = x[src];
        float ev = xs * cs + xd * cd;
        ev = ev > 0.f ? ev : NEG * ev;
        float p = vld ? __expf(ev) : 0.f;
        num += p * xs;
        den += p;
    }
    num += __shfl_xor(num, 4);  num += __shfl_xor(num, 8);
    num += __shfl_xor(num, 16); num += __shfl_xor(num, 32);
    den += __shfl_xor(den, 4);  den += __shfl_xor(den, 8);
    den += __shfl_xor(den, 16); den += __shfl_xor(den, 32);
    float nh = __shfl(num, lane >> 4);
    float dh = __shfl(den, lane >> 4);
    float val = nh / (dh + 1e-16f);
    float hv = val * W0l[lane] + bl[lane];
    hout[((size_t)wv << 6) + lane] = __float2half(hv);
}

// ---------------- 64x64 transform: tiled GEMM + fp8 + es/ed epilogue ----------------

__global__ __launch_bounds__(256) void transform64_k(const __half* __restrict__ hin, const float* __restrict__ W,
                                                     const float* __restrict__ as_, const float* __restrict__ ad_,
                                                     unsigned char* __restrict__ h8, float* __restrict__ es, float* __restrict__ ed) {
    __shared__ float At[64 * TN];   // At[k][n], 32 KB
    __shared__ float Wl[64 * 64];   // 16 KB
    int tid = threadIdx.x;
    for (int i = tid; i < 4096; i += 256) Wl[i] = W[i];
    int n0 = blockIdx.x * TN;
    {   // stage h tile transposed into At (fp16 -> fp32)
        int row = tid >> 1, hf = tid & 1;
        int n = n0 + row;
        const uint4* src = (const uint4*)(hin + ((size_t)n << 6) + (hf << 5));
#pragma unroll
        for (int i = 0; i < 4; i++) {
            uint4 raw = make_uint4(0, 0, 0, 0);
            if (n < NN) raw = src[i];
            __half2* hh = (__half2*)&raw;
            int c = (hf << 5) + (i << 3);
#pragma unroll
            for (int j = 0; j < 4; j++) {
                float2 f = __half22float2(hh[j]);
                At[(c + 2 * j) * TN + row]     = f.x;
                At[(c + 2 * j + 1) * TN + row] = f.y;
            }
        }
    }
    __syncthreads();
    int c = tid & 15, r = tid >> 4;
    float acc[8][4];
#pragma unroll
    for (int i = 0; i < 8; i++)
#pragma unroll
        for (int j = 0; j < 4; j++) acc[i][j] = 0.f;
#pragma unroll 4
    for (int k = 0; k < 64; k++) {
        float4 a0 = *(float4*)&At[k * TN + r * 8];
        float4 a1 = *(float4*)&At[k * TN + r * 8 + 4];
        float4 w  = *(float4*)&Wl[k * 64 + c * 4];
        float av[8] = {a0.x, a0.y, a0.z, a0.w, a1.x, a1.y, a1.z, a1.w};
#pragma unroll
        for (int i = 0; i < 8; i++) {
            acc[i][0] += av[i] * w.x; acc[i][1] += av[i] * w.y;
            acc[i][2] += av[i] * w.z; acc[i][3] += av[i] * w.w;
        }
    }
    int head = c >> 2, qq = c & 3;
    float as0v = as_[head * 16 + qq * 4], as1v = as_[head * 16 + qq * 4 + 1];
    float as2v = as_[head * 16 + qq * 4 + 2], as3v = as_[head * 16 + qq * 4 + 3];
    float ad0v = ad_[head * 16 + qq * 4], ad1v = ad_[head * 16 + qq * 4 + 1];
    float ad2v = ad_[head * 16 + qq * 4 + 2], ad3v = ad_[head * 16 + qq * 4 + 3];
#pragma unroll
    for (int i = 0; i < 8; i++) {
        int n = n0 + r * 8 + i;
        float pes = acc[i][0] * as0v + acc[i][1] * as1v + acc[i][2] * as2v + acc[i][3] * as3v;
        float ped = acc[i][0] * ad0v + acc[i][1] * ad1v + acc[i][2] * ad2v + acc[i][3] * ad3v;
        pes += __shfl_xor(pes, 1); pes += __shfl_xor(pes, 2);
        ped += __shfl_xor(ped, 1); ped += __shfl_xor(ped, 2);
        if (n < NN) {
            unsigned rq = pk_fp8x4(acc[i][0], acc[i][1], acc[i][2], acc[i][3]);
            *(unsigned*)(h8 + ((size_t)n << 6) + (c << 2)) = rq;
            if (qq == 0) { es[n * 4 + head] = pes; ed[n * 4 + head] = ped; }
        }
    }
}

// ---------------- Fused edge softmax + gather ----------------
// Best-measured config (r12): 2 nodes/wave, NO k-unroll, packed-f32
// accumulation, natural node order. lane = q*8+j; head = j>>1.
// Self-loops guarantee deg>=1. Max-subtraction dropped: |e| = O(1).

__global__ __launch_bounds__(256) void gather_k(const unsigned char* __restrict__ h8, const float* __restrict__ es,
                                                const float* __restrict__ ed, const int* __restrict__ rowptr,
                                                const int* __restrict__ edge_src, const float* __restrict__ b,
                                                __half* __restrict__ hout) {
    int pr = (blockIdx.x * 256 + threadIdx.x) >> 6;
    int lane = threadIdx.x & 63;
    int nA = pr * 2;
    if (nA >= NN) return;
    int nB = nA + 1;
    bool hasB = nB < NN;
    int q = lane >> 3, j = lane & 7, head = j >> 1;
    const unsigned char* h8j = h8 + (j << 3);
    int begA = rowptr[nA], endA = rowptr[nA + 1];
    int begB = hasB ? rowptr[nB] : begA, endB = hasB ? rowptr[nB + 1] : begA;
    float edvA = ed[nA * 4 + head];
    float edvB = hasB ? ed[nB * 4 + head] : 0.f;
    floatx2 accA[4], accB[4];
#pragma unroll
    for (int t = 0; t < 4; t++) { accA[t] = (floatx2)(0.f); accB[t] = (floatx2)(0.f); }
    float sA = 0.f, sB = 0.f;
    int iters = max((endA - begA + 7) >> 3, (endB - begB + 7) >> 3);
    for (int k = 0; k < iters; k++) {
        int eA = begA + (k << 3) + q;
        int eB = begB + (k << 3) + q;
        bool vA = eA < endA;
        bool vB = eB < endB;
        int srcA = edge_src[vA ? eA : begA];
        int srcB = edge_src[vB ? eB : begB];
        uint2 rawA = *(const uint2*)(h8j + ((unsigned)srcA << 6));
        float esvA = es[srcA * 4 + head];
        uint2 rawB = *(const uint2*)(h8j + ((unsigned)srcB << 6));
        float esvB = es[srcB * 4 + head];
        float evA = esvA + edvA; evA = evA > 0.f ? evA : NEG * evA;
        float evB = esvB + edvB; evB = evB > 0.f ? evB : NEG * evB;
        float pA = vA ? __expf(evA) : 0.f;
        float pB = vB ? __expf(evB) : 0.f;
        accum_fp8p(rawA, pA, accA);
        accum_fp8p(rawB, pB, accB);
        sA += pA;
        sB += pB;
    }
    float fA[8], fB[8];
#pragma unroll
    for (int t = 0; t < 4; t++) {
        fA[2 * t] = accA[t][0]; fA[2 * t + 1] = accA[t][1];
        fB[2 * t] = accB[t][0]; fB[2 * t + 1] = accB[t][1];
    }
#pragma unroll
    for (int t = 0; t < 8; t++) {
        fA[t] += __shfl_xor(fA[t], 8);
        fA[t] += __shfl_xor(fA[t], 16);
        fA[t] += __shfl_xor(fA[t], 32);
        fB[t] += __shfl_xor(fB[t], 8);
        fB[t] += __shfl_xor(fB[t], 16);
        fB[t] += __shfl_xor(fB[t], 32);
    }
    sA += __shfl_xor(sA, 8); sA += __shfl_xor(sA, 16); sA += __shfl_xor(sA, 32);
    sB += __shfl_xor(sB, 8); sB += __shfl_xor(sB, 16); sB += __shfl_xor(sB, 32);
    if (q == 0) {
        const float4* bp = (const float4*)(b + j * 8);
        float4 b0 = bp[0], b1 = bp[1];
        {
            float inv = 1.0f / (sA + 1e-16f);
            union { __half2 h2[4]; uint4 u; } pk;
            pk.h2[0] = __floats2half2_rn(fA[0] * inv + b0.x, fA[1] * inv + b0.y);
            pk.h2[1] = __floats2half2_rn(fA[2] * inv + b0.z, fA[3] * inv + b0.w);
            pk.h2[2] = __floats2half2_rn(fA[4] * inv + b1.x, fA[5] * inv + b1.y);
            pk.h2[3] = __floats2half2_rn(fA[6] * inv + b1.z, fA[7] * inv + b1.w);
            *(uint4*)(hout + ((size_t)nA << 6) + (j << 3)) = pk.u;
        }
        if (hasB) {
            float inv = 1.0f / (sB + 1e-16f);
            union { __half2 h2[4]; uint4 u; } pk;
            pk.h2[0] = __floats2half2_rn(fB[0] * inv + b0.x, fB[1] * inv + b0.y);
            pk.h2[1] = __floats2half2_rn(fB[2] * inv + b0.z, fB[3] * inv + b0.w);
            pk.h2[2] = __floats2half2_rn(fB[4] * inv + b1.x, fB[5] * inv + b1.y);
            pk.h2[3] = __floats2half2_rn(fB[6] * inv + b1.z, fB[7] * inv + b1.w);
            *(uint4*)(hout + ((size_t)nB << 6) + (j << 3)) = pk.u;
        }
    }
}

// ---------------- MLP + decoder + softmax (tiled, fused) ----------------

__global__ __launch_bounds__(256) void mlp_k(const __half* __restrict__ h, const float* __restrict__ lw1,
                                             const float* __restrict__ lb1, const float* __restrict__ lw2,
                                             const float* __restrict__ lb2, const float* __restrict__ dw,
                                             const float* __restrict__ db, float* __restrict__ out) {
    __shared__ float At[64 * TN];   // h tile transposed; reused as a1t after GEMM1
    __shared__ float W1l[4096];     // lw1; reused as a2t (needs 16*TN=2048)
    __shared__ float W2l[1024];
    __shared__ float dwl[64];
    __shared__ float dbl[4];
    int tid = threadIdx.x;
    for (int i = tid; i < 4096; i += 256) W1l[i] = lw1[i];
    for (int i = tid; i < 1024; i += 256) W2l[i] = lw2[i];
    if (tid < 64) dwl[tid] = dw[tid];
    if (tid < 4) dbl[tid] = db[tid];
    int n0 = blockIdx.x * TN;
    {   // stage
        int row = tid >> 1, hf = tid & 1;
        int n = n0 + row;
        const uint4* src = (const uint4*)(h + ((size_t)n << 6) + (hf << 5));
#pragma unroll
        for (int i = 0; i < 4; i++) {
            uint4 raw = make_uint4(0, 0, 0, 0);
            if (n < NN) raw = src[i];
            __half2* hh = (__half2*)&raw;
            int c = (hf << 5) + (i << 3);
#pragma unroll
            for (int j = 0; j < 4; j++) {
                float2 f = __half22float2(hh[j]);
                At[(c + 2 * j) * TN + row]     = f.x;
                At[(c + 2 * j + 1) * TN + row] = f.y;
            }
        }
    }
    __syncthreads();
    int c = tid & 15, r = tid >> 4;
    float acc[8][4];
#pragma unroll
    for (int i = 0; i < 8; i++)
#pragma unroll
        for (int j = 0; j < 4; j++) acc[i][j] = 0.f;
#pragma unroll 4
    for (int k = 0; k < 64; k++) {
        float4 a0 = *(float4*)&At[k * TN + r * 8];
        float4 a1 = *(float4*)&At[k * TN + r * 8 + 4];
        float4 w  = *(float4*)&W1l[k * 64 + c * 4];
        float av[8] = {a0.x, a0.y, a0.z, a0.w, a1.x, a1.y, a1.z, a1.w};
#pragma unroll
        for (int i = 0; i < 8; i++) {
            acc[i][0] += av[i] * w.x; acc[i][1] += av[i] * w.y;
            acc[i][2] += av[i] * w.z; acc[i][3] += av[i] * w.w;
        }
    }
    float b1v0 = lb1[c * 4], b1v1 = lb1[c * 4 + 1], b1v2 = lb1[c * 4 + 2], b1v3 = lb1[c * 4 + 3];
    __syncthreads();
#pragma unroll
    for (int i = 0; i < 8; i++) {
        int n = r * 8 + i;
        At[(c * 4 + 0) * TN + n] = fmaxf(acc[i][0] + b1v0, 0.f);
        At[(c * 4 + 1) * TN + n] = fmaxf(acc[i][1] + b1v1, 0.f);
        At[(c * 4 + 2) * TN + n] = fmaxf(acc[i][2] + b1v2, 0.f);
        At[(c * 4 + 3) * TN + n] = fmaxf(acc[i][3] + b1v3, 0.f);
    }
    __syncthreads();
    float acc2[8];
#pragma unroll
    for (int i = 0; i < 8; i++) acc2[i] = 0.f;
#pragma unroll 4
    for (int k = 0; k < 64; k++) {
        float4 a0 = *(float4*)&At[k * TN + r * 8];
        float4 a1 = *(float4*)&At[k * TN + r * 8 + 4];
        float wv = W2l[k * 16 + c];
        acc2[0] += a0.x * wv; acc2[1] += a0.y * wv; acc2[2] += a0.z * wv; acc2[3] += a0.w * wv;
        acc2[4] += a1.x * wv; acc2[5] += a1.y * wv; acc2[6] += a1.z * wv; acc2[7] += a1.w * wv;
    }
    float b2v = lb2[c];
#pragma unroll
    for (int i = 0; i < 8; i++) W1l[c * TN + r * 8 + i] = acc2[i] + b2v;  // a2t[col][node]
    __syncthreads();
    if (tid < TN) {
        int n = n0 + tid;
        if (n < NN) {
            float lg0 = dbl[0], lg1 = dbl[1], lg2 = dbl[2], lg3 = dbl[3];
#pragma unroll
            for (int k = 0; k < 16; k++) {
                float a = W1l[k * TN + tid];
                lg0 += a * dwl[k * 4];     lg1 += a * dwl[k * 4 + 1];
                lg2 += a * dwl[k * 4 + 2]; lg3 += a * dwl[k * 4 + 3];
            }
            float mx = fmaxf(fmaxf(lg0, lg1), fmaxf(lg2, lg3));
            float e0 = __expf(lg0 - mx), e1 = __expf(lg1 - mx), e2 = __expf(lg2 - mx), e3 = __expf(lg3 - mx);
            float inv = 1.0f / (e0 + e1 + e2 + e3);
            *(float4*)(out + (size_t)n * 4) = make_float4(e0 * inv, e1 * inv, e2 * inv, e3 * inv);
        }
    }
}

// ---------------- launch ----------------

extern "C" void kernel_launch(void* const* d_in, const int* in_sizes, int n_in,
                              void* d_out, int out_size, void* d_ws, size_t ws_size,
                              hipStream_t stream) {
    const float* x   = (const float*)d_in[0];
    const int*   ei  = (const int*)d_in[1];
    const float* W0  = (const float*)d_in[2];
    const float* as0 = (const float*)d_in[3];
    const float* ad0 = (const float*)d_in[4];
    const float* b0  = (const float*)d_in[5];
    const float* W1  = (const float*)d_in[6];
    const float* as1 = (const float*)d_in[7];
    const float* ad1 = (const float*)d_in[8];
    const float* b1  = (const float*)d_in[9];
    const float* W2  = (const float*)d_in[10];
    const float* as2 = (const float*)d_in[11];
    const float* ad2 = (const float*)d_in[12];
    const float* b2  = (const float*)d_in[13];
    const float* lw1 = (const float*)d_in[14];
    const float* lb1 = (const float*)d_in[15];
    const float* lw2 = (const float*)d_in[16];
    const float* lb2 = (const float*)d_in[17];
    const float* dw  = (const float*)d_in[18];
    const float* db  = (const float*)d_in[19];
    float* out = (float*)d_out;

    char* p = (char*)d_ws;
    size_t off = 0;
    auto alloc = [&](size_t n) -> void* {
        void* r = p + off;
        off = (off + n + 255) & ~(size_t)255;
        return r;
    };
    __half* hB     = (__half*)alloc((size_t)NN * 64 * 2);
    __half* hC     = (__half*)alloc((size_t)NN * 64 * 2);
    unsigned char* h8 = (unsigned char*)alloc((size_t)NN * 64);
    float*  es     = (float*)alloc((size_t)NN * 4 * 4);
    float*  ed     = (float*)alloc((size_t)NN * 4 * 4);
    int*    rowptr = (int*)alloc((size_t)(NN + 1) * 4);
    int*    edge_src = (int*)alloc((size_t)EP * 4);
    unsigned int* arena = (unsigned int*)alloc((size_t)NB * SSTRIDE * 4);
    int*    gcur   = (int*)alloc(512 * 4);
    int*    bbase  = (int*)alloc(513 * 4);

    hipMemsetAsync(gcur, 0, 512 * 4, stream);

    partition_k<<<(EP + CHUNK - 1) / CHUNK, 512, 0, stream>>>(ei, gcur, arena);
    bscan_k<<<1, 512, 0, stream>>>(gcur, bbase, rowptr);
    csr_scatter_k<<<NB, 512, 0, stream>>>(bbase, gcur, arena, rowptr, edge_src);

    int nb_tile = (NN + TN - 1) / TN;       // 782
    int nb_wave = (NN + 3) / 4;             // 25000
    int nb_pair = ((NN + 1) / 2 + 3) / 4;   // 12500 (2 nodes per wave)

    gather0_k<<<nb_wave, 256, 0, stream>>>(x, W0, as0, ad0, rowptr, edge_src, b0, hB);

    transform64_k<<<nb_tile, 256, 0, stream>>>(hB, W1, as1, ad1, h8, es, ed);
    gather_k<<<nb_pair, 256, 0, stream>>>(h8, es, ed, rowptr, edge_src, b1, hC);

    transform64_k<<<nb_tile, 256, 0, stream>>>(hC, W2, as2, ad2, h8, es, ed);
    gather_k<<<nb_pair, 256, 0, stream>>>(h8, es, ed, rowptr, edge_src, b2, hB);

    mlp_k<<<nb_tile, 256, 0, stream>>>(hB, lw1, lb1, lw2, lb2, dw, db, out);
}